// Round 5
// baseline (4448.960 us; speedup 1.0000x reference)
//
#include <hip/hip_runtime.h>
#include <math.h>

#define Bb   16
#define Tt   2048
#define Dd   1024
#define NL   4
#define MTOT (Bb * Tt)   // 32768

typedef float f32x4 __attribute__((ext_vector_type(4)));
typedef short bf16x8 __attribute__((ext_vector_type(8)));

// ---------------------------------------------------------------------------
__device__ __forceinline__ unsigned short f2bf_rne(float x) {
    unsigned u = __float_as_uint(x);
    u += 0x7fffu + ((u >> 16) & 1u);
    return (unsigned short)(u >> 16);
}
__device__ __forceinline__ float bf2f(unsigned short h) {
    return __uint_as_float(((unsigned)h) << 16);
}
__device__ __forceinline__ float gelu_tanh(float x) {
    float x3 = x * x * x;
    float u  = 0.7978845608028654f * (x + 0.044715f * x3);
    return 0.5f * x * (1.0f + tanhf(u));
}

// ---------------------------------------------------------------------------
// Split + transpose [1024,1024] fp32 -> bf16 hi/lo, output [n][k].
// ---------------------------------------------------------------------------
__global__ __launch_bounds__(256)
void split_bt(const float* __restrict__ B, short* __restrict__ ht,
              short* __restrict__ lt)
{
    __shared__ float tile[32][33];
    const int t  = threadIdx.x;
    const int r  = t >> 3;
    const int c  = (t & 7) * 4;
    const int kb = blockIdx.y * 32;
    const int nb = blockIdx.x * 32;
    float4 v = *reinterpret_cast<const float4*>(
        &B[(size_t)(kb + r) * Dd + nb + c]);
    tile[r][c + 0] = v.x; tile[r][c + 1] = v.y;
    tile[r][c + 2] = v.z; tile[r][c + 3] = v.w;
    __syncthreads();
    unsigned h[4], lo[4];
#pragma unroll
    for (int q = 0; q < 4; ++q) {
        float f = tile[c + q][r];
        unsigned short hh = f2bf_rne(f);
        float rem = f - bf2f(hh);
        h[q]  = hh;
        lo[q] = f2bf_rne(rem);
    }
    uint2 hw, lw;
    hw.x = h[0]  | (h[1]  << 16); hw.y = h[2]  | (h[3]  << 16);
    lw.x = lo[0] | (lo[1] << 16); lw.y = lo[2] | (lo[3] << 16);
    size_t off = (size_t)(nb + r) * Dd + kb + c;
    *reinterpret_cast<uint2*>(&ht[off]) = hw;
    *reinterpret_cast<uint2*>(&lt[off]) = lw;
}

// ---------------------------------------------------------------------------
// Unified split-precision MFMA GEMM (fp32 via 3 bf16 MFMAs).
// Tile 128x256, BK=32, 256 thr = 4 waves (2x2: each wave 64x128 output).
// MODE 0: Cout = A@B (+bias)                                grid (4, M/128)
// MODE 1: Cout[t] = Sin[t] + (t%Tt>=m ? A[t-m]@B : 0)       grid (4, 256)
// MODE 2: rows [tstart,tstart+128) of each batch:
//         Cout[r] = Sin[r] + A[r-128]@B                     grid (4, 16)
// BN 1: also emit per-(m-tile, column) partial sum/sumsq of the output.
// Proven 2-barrier structure, loads staged between barriers, no xcd remap.
// ---------------------------------------------------------------------------
template<int MODE, int BN>
__global__ __launch_bounds__(256, 2)
void mfma_gemm(const float* __restrict__ A,
               const short* __restrict__ Bth, const short* __restrict__ Btl,
               const float* __restrict__ bias,
               const float* __restrict__ Sin,
               float* __restrict__ Cout,
               float* __restrict__ psum, float* __restrict__ psq,
               int m, int tstart)
{
    // Ah @ 0, Al @ 5120, Bh @ 10240, Bl @ 20480   (shorts; rows padded to 40)
    __shared__ __align__(16) short lds[30720];
    __shared__ float bnS[BN ? 256 : 1];
    __shared__ float bnQ[BN ? 256 : 1];
    const int tid  = threadIdx.x;
    const int lane = tid & 63;
    const int w    = tid >> 6;
    const int n0   = blockIdx.x * 256;
    const int m0g  = (MODE == 2) ? (blockIdx.y * Tt + tstart)
                                 : (blockIdx.y * 128);
    const int wm0  = (w >> 1) * 64;
    const int wn0  = (w & 1) * 128;
    const int ar   = tid >> 3;
    const int ac   = (tid & 7) * 4;
    const int bnr  = tid >> 2;
    const int bsg  = tid & 3;

    if (BN) { bnS[tid] = 0.f; bnQ[tid] = 0.f; }

    int  arow_src[4];
    bool avalid[4];
#pragma unroll
    for (int p = 0; p < 4; ++p) {
        int rg = m0g + p * 32 + ar;
        bool v = true;
        if (MODE >= 1) { int t = rg & (Tt - 1); v = (t >= m); }
        avalid[p]   = v;
        arow_src[p] = (MODE >= 1 && v) ? (rg - m) : rg;
    }

    f32x4 acc[4][8];
#pragma unroll
    for (int i = 0; i < 4; ++i)
#pragma unroll
        for (int j = 0; j < 8; ++j) acc[i][j] = (f32x4){0.f, 0.f, 0.f, 0.f};

    int a_off[4];
#pragma unroll
    for (int i = 0; i < 4; ++i) {
        int r = wm0 + i * 16 + (lane & 15);
        a_off[i] = r * 40 + (lane >> 4) * 8;
    }
    const int b_off0 = 10240 + (wn0 + (lane & 15)) * 40 + (lane >> 4) * 8;

    for (int k0 = 0; k0 < Dd; k0 += 32) {
        __syncthreads();   // previous tile's ds_reads complete
        // ---- stage A: global fp32 -> (hi, lo) bf16 -> LDS ----
#pragma unroll
        for (int p = 0; p < 4; ++p) {
            float4 v = *reinterpret_cast<const float4*>(
                &A[(size_t)arow_src[p] * Dd + k0 + ac]);
            if (MODE >= 1 && !avalid[p]) v = make_float4(0.f, 0.f, 0.f, 0.f);
            int wo = (p * 32 + ar) * 40 + ac;
            unsigned short h0 = f2bf_rne(v.x), h1 = f2bf_rne(v.y),
                           h2 = f2bf_rne(v.z), h3 = f2bf_rne(v.w);
            unsigned short g0 = f2bf_rne(v.x - bf2f(h0)),
                           g1 = f2bf_rne(v.y - bf2f(h1)),
                           g2 = f2bf_rne(v.z - bf2f(h2)),
                           g3 = f2bf_rne(v.w - bf2f(h3));
            uint2 hw, lw;
            hw.x = (unsigned)h0 | ((unsigned)h1 << 16);
            hw.y = (unsigned)h2 | ((unsigned)h3 << 16);
            lw.x = (unsigned)g0 | ((unsigned)g1 << 16);
            lw.y = (unsigned)g2 | ((unsigned)g3 << 16);
            *reinterpret_cast<uint2*>(&lds[wo])        = hw;
            *reinterpret_cast<uint2*>(&lds[wo + 5120]) = lw;
        }
        // ---- stage B (256 rows): copy pre-split bf16 ----
#pragma unroll
        for (int q = 0; q < 4; ++q) {
            int n = q * 64 + bnr;
            size_t g = (size_t)(n0 + n) * Dd + k0 + bsg * 8;
            int wo = 10240 + n * 40 + bsg * 8;
            *reinterpret_cast<int4*>(&lds[wo]) =
                *reinterpret_cast<const int4*>(&Bth[g]);
            *reinterpret_cast<int4*>(&lds[wo + 10240]) =
                *reinterpret_cast<const int4*>(&Btl[g]);
        }
        __syncthreads();
        // ---- compute ----
        bf16x8 ah[4], al[4];
#pragma unroll
        for (int i = 0; i < 4; ++i) {
            ah[i] = *reinterpret_cast<const bf16x8*>(&lds[a_off[i]]);
            al[i] = *reinterpret_cast<const bf16x8*>(&lds[a_off[i] + 5120]);
        }
#pragma unroll
        for (int j = 0; j < 8; ++j) {
            int bo = b_off0 + j * 640;
            bf16x8 bh = *reinterpret_cast<const bf16x8*>(&lds[bo]);
            bf16x8 bl = *reinterpret_cast<const bf16x8*>(&lds[bo + 10240]);
#pragma unroll
            for (int i = 0; i < 4; ++i) {
                acc[i][j] = __builtin_amdgcn_mfma_f32_16x16x32_bf16(
                    ah[i], bh, acc[i][j], 0, 0, 0);
                acc[i][j] = __builtin_amdgcn_mfma_f32_16x16x32_bf16(
                    ah[i], bl, acc[i][j], 0, 0, 0);
                acc[i][j] = __builtin_amdgcn_mfma_f32_16x16x32_bf16(
                    al[i], bh, acc[i][j], 0, 0, 0);
            }
        }
    }

    // ---- epilogue ----
#pragma unroll
    for (int j = 0; j < 8; ++j) {
        int cl  = wn0 + j * 16 + (lane & 15);
        int col = n0 + cl;
        float bj = (MODE == 0 && bias) ? bias[col] : 0.f;
        float sv = 0.f, sq = 0.f;
#pragma unroll
        for (int i = 0; i < 4; ++i) {
            int rbase = m0g + wm0 + i * 16 + (lane >> 4) * 4;
#pragma unroll
            for (int e = 0; e < 4; ++e) {
                size_t off = (size_t)(rbase + e) * Dd + col;
                float v = acc[i][j][e] + bj;
                if (MODE >= 1) v += Sin[off];
                Cout[off] = v;
                if (BN) { sv += v; sq += v * v; }
            }
        }
        if (BN) { atomicAdd(&bnS[cl], sv); atomicAdd(&bnQ[cl], sq); }
    }
    if (BN) {
        __syncthreads();
        psum[(size_t)blockIdx.y * Dd + n0 + tid] = bnS[tid];
        psq [(size_t)blockIdx.y * Dd + n0 + tid] = bnQ[tid];
    }
}

// ---------------------------------------------------------------------------
__global__ __launch_bounds__(256)
void bn_stats(const float* __restrict__ ps, const float* __restrict__ pq,
              const float* __restrict__ scale, const float* __restrict__ bias,
              float* __restrict__ Av, float* __restrict__ Cv)
{
    const int d = blockIdx.x * 256 + threadIdx.x;
    float s = 0.f, q = 0.f;
    for (int p = 0; p < 256; ++p) {
        s += ps[p * Dd + d];
        q += pq[p * Dd + d];
    }
    const float invN = 1.0f / 32768.0f;
    float mean = s * invN;
    float var  = q * invN - mean * mean;
    float rs   = rsqrtf(var + 1e-5f);
    float a    = rs * scale[d];
    Av[d] = a;
    Cv[d] = bias[d] - mean * a;
}

// ---------------------------------------------------------------------------
__global__ __launch_bounds__(256)
void residual_gelu(const float* __restrict__ Z, const float* __restrict__ Yin,
                   float* __restrict__ Yout,
                   const float* __restrict__ Av, const float* __restrict__ Cv)
{
    const float4* z4 = reinterpret_cast<const float4*>(Z);
    const float4* y4 = reinterpret_cast<const float4*>(Yin);
    float4*       o4 = reinterpret_cast<float4*>(Yout);
    const float4* a4 = reinterpret_cast<const float4*>(Av);
    const float4* c4 = reinterpret_cast<const float4*>(Cv);
    const int n4 = MTOT * Dd / 4;
    for (int i = blockIdx.x * blockDim.x + threadIdx.x; i < n4;
         i += gridDim.x * blockDim.x) {
        int d4 = i & (Dd / 4 - 1);
        float4 z = z4[i], y = y4[i], a = a4[d4], c = c4[d4];
        float4 o;
        o.x = gelu_tanh(fmaf(z.x, a.x, c.x)) + y.x;
        o.y = gelu_tanh(fmaf(z.y, a.y, c.y)) + y.y;
        o.z = gelu_tanh(fmaf(z.z, a.z, c.z)) + y.z;
        o.w = gelu_tanh(fmaf(z.w, a.w, c.w)) + y.w;
        o4[i] = o;
    }
}

// ---------------------------------------------------------------------------
extern "C" void kernel_launch(void* const* d_in, const int* in_sizes, int n_in,
                              void* d_out, int out_size, void* d_ws, size_t ws_size,
                              hipStream_t stream)
{
    const float* x    = (const float*)d_in[0];
    const float* Wi   = (const float*)d_in[1];
    const float* bi   = (const float*)d_in[2];
    const float* Wh   = (const float*)d_in[3];
    const float* mlpW = (const float*)d_in[4];
    const float* mlpb = (const float*)d_in[5];
    const float* bns  = (const float*)d_in[6];
    const float* bnb  = (const float*)d_in[7];
    float* out = (float*)d_out;

    float* ws   = (float*)d_ws;
    float* S0   = ws;                                  // 32M floats (128 MiB)
    float* Pa   = S0 + (size_t)MTOT * Dd;
    float* Pb   = Pa + (size_t)Dd * Dd;
    float* psum = Pb + (size_t)Dd * Dd;                // [256][1024]
    float* psq  = psum + 256 * Dd;
    float* abuf = psq + 256 * Dd;
    float* cbuf = abuf + Dd;
    short* Bth  = (short*)(cbuf + Dd);
    short* Btl  = Bth + (size_t)Dd * Dd;

    const dim3 gBig(4, 256);
    const dim3 gSq (4, 8);
    const dim3 gSeq(4, 16);
    const dim3 gBt (32, 32);

#define SPLIT(M) split_bt<<<gBt, 256, 0, stream>>>((M), Bth, Btl)
#define GEMM(MODE, BN, grid, A_, bias_, Sin_, C_, ps_, pq_, m_, ts_)          \
    mfma_gemm<MODE, BN><<<grid, 256, 0, stream>>>(                            \
        (A_), Bth, Btl, (bias_), (Sin_), (C_), (ps_), (pq_), (m_), (ts_))

    // Phase 1: xp = x @ Wi + bi -> S0
    SPLIT(Wi);
    GEMM(0, 0, gBig, x, bi, nullptr, S0, nullptr, nullptr, 0, 0);

    // Phase 2: 7 scan-doubling levels (window 128), powers interleaved.
    SPLIT(Wh);
    GEMM(1, 0, gBig, S0, nullptr, S0, out, nullptr, nullptr, 1, 0);   // L1
    GEMM(0, 0, gSq,  Wh, nullptr, nullptr, Pa, nullptr, nullptr, 0, 0); // P2
    SPLIT(Pa);
    GEMM(1, 0, gBig, out, nullptr, out, S0, nullptr, nullptr, 2, 0);  // L2
    GEMM(0, 0, gSq,  Pa, nullptr, nullptr, Pb, nullptr, nullptr, 0, 0); // P4
    SPLIT(Pb);
    GEMM(1, 0, gBig, S0, nullptr, S0, out, nullptr, nullptr, 4, 0);   // L3
    GEMM(0, 0, gSq,  Pb, nullptr, nullptr, Pa, nullptr, nullptr, 0, 0); // P8
    SPLIT(Pa);
    GEMM(1, 0, gBig, out, nullptr, out, S0, nullptr, nullptr, 8, 0);  // L4
    GEMM(0, 0, gSq,  Pa, nullptr, nullptr, Pb, nullptr, nullptr, 0, 0); // P16
    SPLIT(Pb);
    GEMM(1, 0, gBig, S0, nullptr, S0, out, nullptr, nullptr, 16, 0);  // L5
    GEMM(0, 0, gSq,  Pb, nullptr, nullptr, Pa, nullptr, nullptr, 0, 0); // P32
    SPLIT(Pa);
    GEMM(1, 0, gBig, out, nullptr, out, S0, nullptr, nullptr, 32, 0); // L6
    GEMM(0, 0, gSq,  Pa, nullptr, nullptr, Pb, nullptr, nullptr, 0, 0); // P64
    SPLIT(Pb);
    GEMM(1, 0, gBig, S0, nullptr, S0, out, nullptr, nullptr, 64, 0);  // L7 -> out
    GEMM(0, 0, gSq,  Pb, nullptr, nullptr, Pa, nullptr, nullptr, 0, 0); // P128
    SPLIT(Pa);

    // Phase 3: 15 sequential carry steps with P128 (in-place on out)
    for (int i = 1; i < 16; ++i)
        GEMM(2, 0, gSeq, out, nullptr, out, out, nullptr, nullptr, 128, 128 * i);

    // Phase 4: residual MLP stack; y stays in out, z in S0
    for (int l = 0; l < NL; ++l) {
        SPLIT(mlpW + (size_t)l * Dd * Dd);
        GEMM(0, 1, gBig, out, mlpb + (size_t)l * Dd, nullptr, S0, psum, psq, 0, 0);
        bn_stats<<<4, 256, 0, stream>>>(psum, psq, bns + (size_t)l * Dd,
                                        bnb + (size_t)l * Dd, abuf, cbuf);
        residual_gelu<<<2048, 256, 0, stream>>>(S0, out, out, abuf, cbuf);
    }
#undef SPLIT
#undef GEMM
}

// Round 6
// 3788.747 us; speedup vs baseline: 1.1743x; 1.1743x over previous
//
#include <hip/hip_runtime.h>
#include <math.h>

#define Bb   16
#define Tt   2048
#define Dd   1024
#define NL   4
#define MTOT (Bb * Tt)   // 32768

typedef float f32x4 __attribute__((ext_vector_type(4)));
typedef short bf16x8 __attribute__((ext_vector_type(8)));

// ---------------------------------------------------------------------------
__device__ __forceinline__ unsigned short f2bf_rne(float x) {
    unsigned u = __float_as_uint(x);
    u += 0x7fffu + ((u >> 16) & 1u);
    return (unsigned short)(u >> 16);
}
__device__ __forceinline__ float bf2f(unsigned short h) {
    return __uint_as_float(((unsigned)h) << 16);
}
__device__ __forceinline__ float gelu_tanh(float x) {
    float x3 = x * x * x;
    float u  = 0.7978845608028654f * (x + 0.044715f * x3);
    return 0.5f * x * (1.0f + tanhf(u));
}
// async 16B global -> LDS (HW: wave-uniform LDS base + lane*16)
__device__ __forceinline__ void dma16(const void* g, void* l) {
    __builtin_amdgcn_global_load_lds(
        (const __attribute__((address_space(1))) unsigned int*)g,
        (__attribute__((address_space(3))) unsigned int*)l, 16, 0, 0);
}

// ---------------------------------------------------------------------------
// Split a [1024,1024] fp32 matrix (row-major [k][n]) into bf16 hi/lo with
// k-tiled, slot-swizzled layout:
//   fragment (n, kt, sl) -> shorts offset ((kt*1024+n)*4 + (sl^((n>>1)&3)))*8
// so the GEMM can DMA each k-tile linearly into LDS and read conflict-free.
// ---------------------------------------------------------------------------
__global__ __launch_bounds__(256)
void split_bt(const float* __restrict__ B, short* __restrict__ ht,
              short* __restrict__ lt)
{
    __shared__ float tile[32][33];
    const int t  = threadIdx.x;
    const int r  = t >> 3;          // 0..31
    const int c  = (t & 7) * 4;     // 0,4,...,28
    const int kb = blockIdx.y * 32; // kt = blockIdx.y
    const int nb = blockIdx.x * 32;
    float4 v = *reinterpret_cast<const float4*>(
        &B[(size_t)(kb + r) * Dd + nb + c]);
    tile[r][c + 0] = v.x; tile[r][c + 1] = v.y;
    tile[r][c + 2] = v.z; tile[r][c + 3] = v.w;
    __syncthreads();
    unsigned h[4], lo[4];
#pragma unroll
    for (int q = 0; q < 4; ++q) {
        float f = tile[c + q][r];           // B[kb+c+q][nb+r]
        unsigned short hh = f2bf_rne(f);
        float rem = f - bf2f(hh);
        h[q]  = hh;
        lo[q] = f2bf_rne(rem);
    }
    uint2 hw, lw;
    hw.x = h[0]  | (h[1]  << 16); hw.y = h[2]  | (h[3]  << 16);
    lw.x = lo[0] | (lo[1] << 16); lw.y = lo[2] | (lo[3] << 16);
    const int n = nb + r;
    const int s = (c >> 3) ^ ((n >> 1) & 3);   // swizzled slot
    size_t off = ((size_t)(blockIdx.y * 1024 + n) * 4 + s) * 8 + (c & 4);
    *reinterpret_cast<uint2*>(&ht[off]) = hw;
    *reinterpret_cast<uint2*>(&lt[off]) = lw;
}

// ---------------------------------------------------------------------------
// Unified split-precision MFMA GEMM (fp32 via 3 bf16 MFMAs).
// Tile 128xNT (NT=256 for big GEMMs, NT=128 for squarings / seq carries),
// BK=32, 256 thr = 4 waves (2x2; each wave 64 x NT/2 output).
// MODE 0: Cout = A@B (+bias)
// MODE 1: Cout[t] = Sin[t] + (t%Tt>=m ? A[t-m]@B : 0)
// MODE 2: rows [tstart,tstart+128) of each batch: Cout[r]=Sin[r]+A[r-128]@B
// BN 1:   also emit per-(m-tile, column) partial sum/sumsq (reuses LDS).
// B is DMA'd (global_load_lds x16B) from the pre-swizzled split_bt layout
// into linear LDS [n][32shorts]; reads apply the same XOR -> 2-way only.
// A is reg-staged (needs fp32->hi/lo convert), next tile prefetched during
// compute. 2-barrier structure otherwise unchanged (proven R2/R4/R5).
// ---------------------------------------------------------------------------
template<int MODE, int BN, int NT>
__global__ __launch_bounds__(256, 2)
void mfma_gemm(const float* __restrict__ A,
               const short* __restrict__ Bth, const short* __restrict__ Btl,
               const float* __restrict__ bias,
               const float* __restrict__ Sin,
               float* __restrict__ Cout,
               float* __restrict__ psum, float* __restrict__ psq,
               int m, int tstart)
{
    constexpr int NJ  = NT / 32;        // j-fragments per wave
    constexpr int BH  = 10240;          // B-hi base (shorts); A: [0,10240)
    constexpr int BPL = NT * 32;        // shorts per B plane
    __shared__ __align__(16) short lds[BH + 2 * BPL];
    float* bnF = (float*)lds;           // BN scratch (reused post-compute)

    const int tid  = threadIdx.x;
    const int lane = tid & 63;
    const int w    = tid >> 6;
    const int n0   = blockIdx.x * NT;
    const int m0g  = (MODE == 2) ? (blockIdx.y * Tt + tstart)
                                 : (blockIdx.y * 128);
    const int wm0  = (w >> 1) * 64;
    const int wn0  = (w & 1) * (NT / 2);
    const int ar   = tid >> 3;
    const int ac   = (tid & 7) * 4;

    int  arow_src[4];
    bool avalid[4];
#pragma unroll
    for (int p = 0; p < 4; ++p) {
        int rg = m0g + p * 32 + ar;
        bool v = true;
        if (MODE >= 1) { int t = rg & (Tt - 1); v = (t >= m); }
        avalid[p]   = v;
        arow_src[p] = (MODE >= 1 && v) ? (rg - m) : rg;
    }

    f32x4 acc[4][NJ];
#pragma unroll
    for (int i = 0; i < 4; ++i)
#pragma unroll
        for (int j = 0; j < NJ; ++j) acc[i][j] = (f32x4){0.f, 0.f, 0.f, 0.f};

    int a_off[4];
#pragma unroll
    for (int i = 0; i < 4; ++i) {
        int r = wm0 + i * 16 + (lane & 15);
        a_off[i] = r * 40 + (lane >> 4) * 8;
    }
    const int ln     = lane & 15;
    const int nlb    = wn0 + ln;                       // local n of fragment
    const int b_off0 = BH + nlb * 32 +
                       (((lane >> 4) ^ ((nlb >> 1) & 3)) << 3);

    // prologue: A tile k0=0 -> regs
    float4 aReg[4];
#pragma unroll
    for (int p = 0; p < 4; ++p)
        aReg[p] = *reinterpret_cast<const float4*>(
            &A[(size_t)arow_src[p] * Dd + ac]);

    for (int k0 = 0; k0 < Dd; k0 += 32) {
        __syncthreads();   // previous tile's ds_reads complete
        // ---- stage A: convert regs -> (hi, lo) bf16 -> LDS ----
#pragma unroll
        for (int p = 0; p < 4; ++p) {
            float4 v = aReg[p];
            if (MODE >= 1 && !avalid[p]) v = make_float4(0.f, 0.f, 0.f, 0.f);
            int wo = (p * 32 + ar) * 40 + ac;
            unsigned short h0 = f2bf_rne(v.x), h1 = f2bf_rne(v.y),
                           h2 = f2bf_rne(v.z), h3 = f2bf_rne(v.w);
            unsigned short g0 = f2bf_rne(v.x - bf2f(h0)),
                           g1 = f2bf_rne(v.y - bf2f(h1)),
                           g2 = f2bf_rne(v.z - bf2f(h2)),
                           g3 = f2bf_rne(v.w - bf2f(h3));
            uint2 hw, lw;
            hw.x = (unsigned)h0 | ((unsigned)h1 << 16);
            hw.y = (unsigned)h2 | ((unsigned)h3 << 16);
            lw.x = (unsigned)g0 | ((unsigned)g1 << 16);
            lw.y = (unsigned)g2 | ((unsigned)g3 << 16);
            *reinterpret_cast<uint2*>(&lds[wo])        = hw;
            *reinterpret_cast<uint2*>(&lds[wo + 5120]) = lw;
        }
        // ---- stage B: async DMA this k-tile (linear LDS dest) ----
        {
            const int kt = k0 >> 5;
#pragma unroll
            for (int q = 0; q < NT / 64; ++q) {
                size_t gfo = ((size_t)(kt * 1024 + n0 + q * 64 + (tid >> 2))
                              * 4 + (tid & 3)) * 8;
                dma16(&Bth[gfo], &lds[BH + q * 2048 + w * 512]);
                dma16(&Btl[gfo], &lds[BH + BPL + q * 2048 + w * 512]);
            }
        }
        __syncthreads();   // drains vmcnt (DMA) + lgkm (A writes)
        // ---- prefetch next A tile (hides under MFMA) ----
        if (k0 + 32 < Dd) {
#pragma unroll
            for (int p = 0; p < 4; ++p)
                aReg[p] = *reinterpret_cast<const float4*>(
                    &A[(size_t)arow_src[p] * Dd + k0 + 32 + ac]);
        }
        // ---- compute ----
        bf16x8 ah[4], al[4];
#pragma unroll
        for (int i = 0; i < 4; ++i) {
            ah[i] = *reinterpret_cast<const bf16x8*>(&lds[a_off[i]]);
            al[i] = *reinterpret_cast<const bf16x8*>(&lds[a_off[i] + 5120]);
        }
#pragma unroll
        for (int j = 0; j < NJ; ++j) {
            int bo = b_off0 + j * 512;
            bf16x8 bh = *reinterpret_cast<const bf16x8*>(&lds[bo]);
            bf16x8 bl = *reinterpret_cast<const bf16x8*>(&lds[bo + BPL]);
#pragma unroll
            for (int i = 0; i < 4; ++i) {
                acc[i][j] = __builtin_amdgcn_mfma_f32_16x16x32_bf16(
                    ah[i], bh, acc[i][j], 0, 0, 0);
                acc[i][j] = __builtin_amdgcn_mfma_f32_16x16x32_bf16(
                    ah[i], bl, acc[i][j], 0, 0, 0);
                acc[i][j] = __builtin_amdgcn_mfma_f32_16x16x32_bf16(
                    al[i], bh, acc[i][j], 0, 0, 0);
            }
        }
    }

    // ---- epilogue ----
    if (BN) {
        __syncthreads();               // all LDS reads done; reuse as floats
        bnF[tid] = 0.f; bnF[256 + tid] = 0.f;
        __syncthreads();
    }
#pragma unroll
    for (int j = 0; j < NJ; ++j) {
        int cl  = wn0 + j * 16 + (lane & 15);
        int col = n0 + cl;
        float bj = (MODE == 0 && bias) ? bias[col] : 0.f;
        float sv = 0.f, sq = 0.f;
#pragma unroll
        for (int i = 0; i < 4; ++i) {
            int rbase = m0g + wm0 + i * 16 + (lane >> 4) * 4;
#pragma unroll
            for (int e = 0; e < 4; ++e) {
                size_t off = (size_t)(rbase + e) * Dd + col;
                float v = acc[i][j][e] + bj;
                if (MODE >= 1) v += Sin[off];
                Cout[off] = v;
                if (BN) { sv += v; sq += v * v; }
            }
        }
        if (BN) { atomicAdd(&bnF[cl], sv); atomicAdd(&bnF[256 + cl], sq); }
    }
    if (BN) {
        __syncthreads();
        psum[(size_t)blockIdx.y * Dd + n0 + tid] = bnF[tid];
        psq [(size_t)blockIdx.y * Dd + n0 + tid] = bnF[256 + tid];
    }
}

// ---------------------------------------------------------------------------
__global__ __launch_bounds__(256)
void bn_stats(const float* __restrict__ ps, const float* __restrict__ pq,
              const float* __restrict__ scale, const float* __restrict__ bias,
              float* __restrict__ Av, float* __restrict__ Cv)
{
    const int d = blockIdx.x * 256 + threadIdx.x;
    float s = 0.f, q = 0.f;
    for (int p = 0; p < 256; ++p) {
        s += ps[p * Dd + d];
        q += pq[p * Dd + d];
    }
    const float invN = 1.0f / 32768.0f;
    float mean = s * invN;
    float var  = q * invN - mean * mean;
    float rs   = rsqrtf(var + 1e-5f);
    float a    = rs * scale[d];
    Av[d] = a;
    Cv[d] = bias[d] - mean * a;
}

// ---------------------------------------------------------------------------
__global__ __launch_bounds__(256)
void residual_gelu(const float* __restrict__ Z, const float* __restrict__ Yin,
                   float* __restrict__ Yout,
                   const float* __restrict__ Av, const float* __restrict__ Cv)
{
    const float4* z4 = reinterpret_cast<const float4*>(Z);
    const float4* y4 = reinterpret_cast<const float4*>(Yin);
    float4*       o4 = reinterpret_cast<float4*>(Yout);
    const float4* a4 = reinterpret_cast<const float4*>(Av);
    const float4* c4 = reinterpret_cast<const float4*>(Cv);
    const int n4 = MTOT * Dd / 4;
    for (int i = blockIdx.x * blockDim.x + threadIdx.x; i < n4;
         i += gridDim.x * blockDim.x) {
        int d4 = i & (Dd / 4 - 1);
        float4 z = z4[i], y = y4[i], a = a4[d4], c = c4[d4];
        float4 o;
        o.x = gelu_tanh(fmaf(z.x, a.x, c.x)) + y.x;
        o.y = gelu_tanh(fmaf(z.y, a.y, c.y)) + y.y;
        o.z = gelu_tanh(fmaf(z.z, a.z, c.z)) + y.z;
        o.w = gelu_tanh(fmaf(z.w, a.w, c.w)) + y.w;
        o4[i] = o;
    }
}

// ---------------------------------------------------------------------------
extern "C" void kernel_launch(void* const* d_in, const int* in_sizes, int n_in,
                              void* d_out, int out_size, void* d_ws, size_t ws_size,
                              hipStream_t stream)
{
    const float* x    = (const float*)d_in[0];
    const float* Wi   = (const float*)d_in[1];
    const float* bi   = (const float*)d_in[2];
    const float* Wh   = (const float*)d_in[3];
    const float* mlpW = (const float*)d_in[4];
    const float* mlpb = (const float*)d_in[5];
    const float* bns  = (const float*)d_in[6];
    const float* bnb  = (const float*)d_in[7];
    float* out = (float*)d_out;

    float* ws   = (float*)d_ws;
    float* S0   = ws;                                  // 32M floats (128 MiB)
    float* Pa   = S0 + (size_t)MTOT * Dd;
    float* Pb   = Pa + (size_t)Dd * Dd;
    float* psum = Pb + (size_t)Dd * Dd;                // [256][1024]
    float* psq  = psum + 256 * Dd;
    float* abuf = psq + 256 * Dd;
    float* cbuf = abuf + Dd;
    short* Bth  = (short*)(cbuf + Dd);
    short* Btl  = Bth + (size_t)Dd * Dd;

    const dim3 gBig(4, 256);    // NT=256 tiles: 128x256
    const dim3 gSq (8, 8);      // NT=128 tiles: 128x128 (64 blocks)
    const dim3 gSeq(8, 16);     // NT=128 tiles (128 blocks)
    const dim3 gBt (32, 32);

#define SPLIT(M) split_bt<<<gBt, 256, 0, stream>>>((M), Bth, Btl)
#define GEMM(MODE, BN, NT, grid, A_, bias_, Sin_, C_, ps_, pq_, m_, ts_)      \
    mfma_gemm<MODE, BN, NT><<<grid, 256, 0, stream>>>(                        \
        (A_), Bth, Btl, (bias_), (Sin_), (C_), (ps_), (pq_), (m_), (ts_))

    // Phase 1: xp = x @ Wi + bi -> S0
    SPLIT(Wi);
    GEMM(0, 0, 256, gBig, x, bi, nullptr, S0, nullptr, nullptr, 0, 0);

    // Phase 2: 7 scan-doubling levels (window 128), powers interleaved.
    SPLIT(Wh);
    GEMM(1, 0, 256, gBig, S0, nullptr, S0, out, nullptr, nullptr, 1, 0);   // L1
    GEMM(0, 0, 128, gSq,  Wh, nullptr, nullptr, Pa, nullptr, nullptr, 0, 0); // P2
    SPLIT(Pa);
    GEMM(1, 0, 256, gBig, out, nullptr, out, S0, nullptr, nullptr, 2, 0);  // L2
    GEMM(0, 0, 128, gSq,  Pa, nullptr, nullptr, Pb, nullptr, nullptr, 0, 0); // P4
    SPLIT(Pb);
    GEMM(1, 0, 256, gBig, S0, nullptr, S0, out, nullptr, nullptr, 4, 0);   // L3
    GEMM(0, 0, 128, gSq,  Pb, nullptr, nullptr, Pa, nullptr, nullptr, 0, 0); // P8
    SPLIT(Pa);
    GEMM(1, 0, 256, gBig, out, nullptr, out, S0, nullptr, nullptr, 8, 0);  // L4
    GEMM(0, 0, 128, gSq,  Pa, nullptr, nullptr, Pb, nullptr, nullptr, 0, 0); // P16
    SPLIT(Pb);
    GEMM(1, 0, 256, gBig, S0, nullptr, S0, out, nullptr, nullptr, 16, 0);  // L5
    GEMM(0, 0, 128, gSq,  Pb, nullptr, nullptr, Pa, nullptr, nullptr, 0, 0); // P32
    SPLIT(Pa);
    GEMM(1, 0, 256, gBig, out, nullptr, out, S0, nullptr, nullptr, 32, 0); // L6
    GEMM(0, 0, 128, gSq,  Pa, nullptr, nullptr, Pb, nullptr, nullptr, 0, 0); // P64
    SPLIT(Pb);
    GEMM(1, 0, 256, gBig, S0, nullptr, S0, out, nullptr, nullptr, 64, 0);  // L7
    GEMM(0, 0, 128, gSq,  Pb, nullptr, nullptr, Pa, nullptr, nullptr, 0, 0); // P128
    SPLIT(Pa);

    // Phase 3: 15 sequential carry steps with P128 (in-place on out)
    for (int i = 1; i < 16; ++i)
        GEMM(2, 0, 128, gSeq, out, nullptr, out, out, nullptr, nullptr,
             128, 128 * i);

    // Phase 4: residual MLP stack; y stays in out, z in S0
    for (int l = 0; l < NL; ++l) {
        SPLIT(mlpW + (size_t)l * Dd * Dd);
        GEMM(0, 1, 256, gBig, out, mlpb + (size_t)l * Dd, nullptr, S0,
             psum, psq, 0, 0);
        bn_stats<<<4, 256, 0, stream>>>(psum, psq, bns + (size_t)l * Dd,
                                        bnb + (size_t)l * Dd, abuf, cbuf);
        residual_gelu<<<2048, 256, 0, stream>>>(S0, out, out, abuf, cbuf);
    }
#undef SPLIT
#undef GEMM
}